// Round 2
// baseline (475.571 us; speedup 1.0000x reference)
//
#include <hip/hip_runtime.h>
#include <hip/hip_bf16.h>

// KAN layer as one bf16 GEMM: out[8192,512] = A[8192,7168] @ W[512,7168]^T + b
//   A = [ silu(x) (512 cols) | b_splines(x) (512*13 cols) ]   built by kan_prep
//   W = [ base_w | spline_w.reshape(512, 6656) ]              built by kan_wconv
// R2: no split-K (atomics were 790 MB of HBM write traffic, 75% of runtime).
//     BM=128 x BN=64 -> 512 blocks = 2/CU; direct-store epilogue with bias.

#define BATCH   8192
#define IN_F    512
#define N_OUT   512
#define NG      13            // GRID_SIZE + K
#define K_TOT   7168          // 512 + 512*13
#define BM      128
#define BN      64
#define BK      64

typedef short short8 __attribute__((ext_vector_type(8)));
typedef float floatx4 __attribute__((ext_vector_type(4)));

__device__ __forceinline__ unsigned short f2bf(float f) {
    union { float f; unsigned u; } v; v.f = f;
    unsigned r = v.u + 0x7FFFu + ((v.u >> 16) & 1u);   // RNE
    return (unsigned short)(r >> 16);
}

// ---------------- W conversion: [512][7168] bf16 ----------------
__global__ void kan_wconv(const float* __restrict__ base_w,
                          const float* __restrict__ spline_w,
                          unsigned short* __restrict__ Wb) {
    int c = blockIdx.x * 256 + threadIdx.x;   // 0..7167  (grid.x = 28)
    int o = blockIdx.y;                        // 0..511
    float v = (c < IN_F) ? base_w[o * IN_F + c]
                         : spline_w[(long)o * (IN_F * NG) + (c - IN_F)];
    Wb[(long)o * K_TOT + c] = f2bf(v);
}

// ---------------- A construction: silu + cubic B-spline bases ----------------
// One block per batch row; stage the 7168-short row in LDS, then write
// fully-coalesced float4's.
__global__ __launch_bounds__(256)
void kan_prep(const float* __restrict__ X,
              unsigned short* __restrict__ A,
              int row0) {
    __shared__ unsigned short rowbuf[K_TOT];   // 14.3 KB
    const int b = blockIdx.x;
    const int tid = threadIdx.x;

#pragma unroll
    for (int e = 0; e < 2; e++) {
        int i = tid + e * 256;                 // 0..511
        float x = X[(long)(row0 + b) * IN_F + i];

        // silu
        float s = x / (1.0f + expf(-x));
        rowbuf[i] = f2bf(s);

        // cubic Cox-de Boor on uniform knots t_j = -3.2 + 0.4j
        float bb[16];
#pragma unroll
        for (int j = 0; j < 16; j++) {
            float t0 = -3.2f + 0.4f * j;
            bb[j] = (x >= t0 && x < t0 + 0.4f) ? 1.0f : 0.0f;
        }
        const float inv1 = 1.0f / (0.4f + 1e-8f);
        const float inv2 = 1.0f / (0.8f + 1e-8f);
        const float inv3 = 1.0f / (1.2f + 1e-8f);
#pragma unroll
        for (int j = 0; j < 15; j++) {
            float tj = -3.2f + 0.4f * j;
            bb[j] = (x - tj) * inv1 * bb[j] + ((tj + 0.8f) - x) * inv1 * bb[j + 1];
        }
#pragma unroll
        for (int j = 0; j < 14; j++) {
            float tj = -3.2f + 0.4f * j;
            bb[j] = (x - tj) * inv2 * bb[j] + ((tj + 1.2f) - x) * inv2 * bb[j + 1];
        }
#pragma unroll
        for (int j = 0; j < 13; j++) {
            float tj = -3.2f + 0.4f * j;
            bb[j] = (x - tj) * inv3 * bb[j] + ((tj + 1.6f) - x) * inv3 * bb[j + 1];
        }
#pragma unroll
        for (int g = 0; g < NG; g++) rowbuf[IN_F + i * NG + g] = f2bf(bb[g]);
    }
    __syncthreads();

    // coalesced writeback: 7168 shorts = 448 float4
    const float4* src = (const float4*)rowbuf;
    float4* dst = (float4*)(A + (long)b * K_TOT);
    for (int t = tid; t < K_TOT / 8; t += 256) dst[t] = src[t];
}

// ---------------- GEMM: C = A @ W^T + bias (bf16 MFMA) ----------------
__global__ __launch_bounds__(256)
void kan_gemm(const unsigned short* __restrict__ A,   // [nrows][7168] bf16 bits
              const unsigned short* __restrict__ Wb,  // [512][7168]  bf16 bits
              const float* __restrict__ bias,         // [512]
              float* __restrict__ out,                // [8192][512] fp32
              int row0) {
    __shared__ unsigned short As[BM][72];   // pad 64->72: spreads banks
    __shared__ unsigned short Bs[BN][72];

    const int tid  = threadIdx.x;
    const int lane = tid & 63;
    const int wave = tid >> 6;
    const int wm   = wave >> 1;      // 0..1  (row half)
    const int wn   = wave & 1;       // 0..1  (col half)
    const int quad = lane >> 4;      // 0..3
    const int l16  = lane & 15;

    const int m0 = blockIdx.x * BM;          // within chunk
    const int n0 = blockIdx.y * BN;

    // staging decode: per issue q, row = q*32 + rr, 16B chunk = tid&7
    const int rr = tid >> 3;                 // 0..31
    const int c8 = (tid & 7) * 8;            // element offset in row

    const unsigned short* pA = A  + (long)(m0 + rr) * K_TOT + c8;
    const unsigned short* pB = Wb + (long)(n0 + rr) * K_TOT + c8;

    floatx4 acc[4][2];
#pragma unroll
    for (int i = 0; i < 4; i++)
#pragma unroll
        for (int j = 0; j < 2; j++) acc[i][j] = (floatx4){0.f, 0.f, 0.f, 0.f};

    float4 ra[4], rb[2];
#pragma unroll
    for (int q = 0; q < 4; q++) ra[q] = *(const float4*)(pA + (long)q * 32 * K_TOT);
#pragma unroll
    for (int q = 0; q < 2; q++) rb[q] = *(const float4*)(pB + (long)q * 32 * K_TOT);

    for (int kk = 0; kk < K_TOT; kk += BK) {
        __syncthreads();                    // prior compute done before overwrite
#pragma unroll
        for (int q = 0; q < 4; q++) *(float4*)&As[q * 32 + rr][c8] = ra[q];
#pragma unroll
        for (int q = 0; q < 2; q++) *(float4*)&Bs[q * 32 + rr][c8] = rb[q];
        __syncthreads();

        pA += BK; pB += BK;
        if (kk + BK < K_TOT) {              // prefetch next tile into regs
#pragma unroll
            for (int q = 0; q < 4; q++) ra[q] = *(const float4*)(pA + (long)q * 32 * K_TOT);
#pragma unroll
            for (int q = 0; q < 2; q++) rb[q] = *(const float4*)(pB + (long)q * 32 * K_TOT);
        }

#pragma unroll
        for (int s = 0; s < 2; s++) {       // two k=32 MFMA steps per BK=64
            short8 af[4], bfr[2];
#pragma unroll
            for (int t = 0; t < 4; t++)
                af[t] = *(const short8*)&As[wm * 64 + t * 16 + l16][s * 32 + quad * 8];
#pragma unroll
            for (int t = 0; t < 2; t++)
                bfr[t] = *(const short8*)&Bs[wn * 32 + t * 16 + l16][s * 32 + quad * 8];
#pragma unroll
            for (int i = 0; i < 4; i++)
#pragma unroll
                for (int j = 0; j < 2; j++)
                    acc[i][j] = __builtin_amdgcn_mfma_f32_16x16x32_bf16(
                        af[i], bfr[j], acc[i][j], 0, 0, 0);
        }
    }

    // epilogue: C/D layout col=lane&15, row=quad*4+reg; direct store + bias
#pragma unroll
    for (int i = 0; i < 4; i++) {
        int grow0 = row0 + m0 + wm * 64 + i * 16 + quad * 4;
#pragma unroll
        for (int j = 0; j < 2; j++) {
            int col = n0 + wn * 32 + j * 16 + l16;
            float bv = bias[col];
#pragma unroll
            for (int r = 0; r < 4; r++)
                out[(long)(grow0 + r) * N_OUT + col] = acc[i][j][r] + bv;
        }
    }
}

extern "C" void kernel_launch(void* const* d_in, const int* in_sizes, int n_in,
                              void* d_out, int out_size, void* d_ws, size_t ws_size,
                              hipStream_t stream) {
    const float* x        = (const float*)d_in[0];
    const float* base_w   = (const float*)d_in[1];
    const float* base_b   = (const float*)d_in[2];
    const float* spline_w = (const float*)d_in[3];
    float* out = (float*)d_out;

    unsigned short* Wb = (unsigned short*)d_ws;            // 512*7168 bf16
    const size_t wbytes = (size_t)N_OUT * K_TOT * 2;       // 7.34 MB
    unsigned short* Abuf = Wb + (size_t)N_OUT * K_TOT;

    // M-chunking so the A buffer fits whatever ws we were given
    size_t avail = (ws_size > wbytes) ? (ws_size - wbytes) : 0;
    long max_rows = (long)(avail / ((size_t)K_TOT * 2));
    int chunk = BATCH;
    while (chunk > 128 && chunk > max_rows) chunk >>= 1;

    kan_wconv<<<dim3(K_TOT / 256, N_OUT), 256, 0, stream>>>(base_w, spline_w, Wb);

    for (int row0 = 0; row0 < BATCH; row0 += chunk) {
        kan_prep<<<dim3(chunk), 256, 0, stream>>>(x, Abuf, row0);
        kan_gemm<<<dim3(chunk / BM, N_OUT / BN), 256, 0, stream>>>(
            Abuf, Wb, base_b, out, row0);
    }
}

// Round 3
// 213.683 us; speedup vs baseline: 2.2256x; 2.2256x over previous
//
#include <hip/hip_runtime.h>
#include <hip/hip_bf16.h>

// KAN layer as one bf16 GEMM: out[8192,512] = A[8192,7168] @ W[512,7168]^T + b
//   A = [ silu(x) (512 cols) | b_splines(x) (512*13 cols) ]   built by kan_prep
//   W = [ base_w | spline_w.reshape(512, 6656) ]              built by kan_wconv
// R3: m97-style GEMM — global_load_lds width-16 staging (no VGPR round trip),
//     unpadded LDS, 128x128 tile, 64x64 wave tile; split-K via workspace
//     partials + reduce kernel (R1's atomics cost 790 MB HBM writes; R2's
//     no-split 512-block version was latency-bound at MfmaUtil 6.4%).

#define BATCH   8192
#define IN_F    512
#define N_OUT   512
#define NG      13            // GRID_SIZE + K
#define K_TOT   7168          // 512 + 512*13
#define BM      128
#define BN      128
#define BK      64
#define KSMAX   4

typedef short short8 __attribute__((ext_vector_type(8)));
typedef float floatx4 __attribute__((ext_vector_type(4)));

__device__ __forceinline__ unsigned short f2bf(float f) {
    union { float f; unsigned u; } v; v.f = f;
    unsigned r = v.u + 0x7FFFu + ((v.u >> 16) & 1u);   // RNE
    return (unsigned short)(r >> 16);
}

__device__ __forceinline__ void gl2lds16(const unsigned short* g, unsigned short* l) {
    __builtin_amdgcn_global_load_lds(
        (const __attribute__((address_space(1))) unsigned int*)g,
        (__attribute__((address_space(3))) unsigned int*)l, 16, 0, 0);
}

// ---------------- W conversion: [512][7168] bf16 ----------------
__global__ void kan_wconv(const float* __restrict__ base_w,
                          const float* __restrict__ spline_w,
                          unsigned short* __restrict__ Wb) {
    int c = blockIdx.x * 256 + threadIdx.x;   // 0..7167  (grid.x = 28)
    int o = blockIdx.y;                        // 0..511
    float v = (c < IN_F) ? base_w[o * IN_F + c]
                         : spline_w[(long)o * (IN_F * NG) + (c - IN_F)];
    Wb[(long)o * K_TOT + c] = f2bf(v);
}

// ---------------- A construction: silu + cubic B-spline bases ----------------
__global__ __launch_bounds__(256)
void kan_prep(const float* __restrict__ X,
              unsigned short* __restrict__ A,
              int row0) {
    __shared__ unsigned short rowbuf[K_TOT];   // 14.3 KB
    const int b = blockIdx.x;
    const int tid = threadIdx.x;

#pragma unroll
    for (int e = 0; e < 2; e++) {
        int i = tid + e * 256;                 // 0..511
        float x = X[(long)(row0 + b) * IN_F + i];

        float s = x / (1.0f + expf(-x));       // silu
        rowbuf[i] = f2bf(s);

        // cubic Cox-de Boor on uniform knots t_j = -3.2 + 0.4j
        float bb[16];
#pragma unroll
        for (int j = 0; j < 16; j++) {
            float t0 = -3.2f + 0.4f * j;
            bb[j] = (x >= t0 && x < t0 + 0.4f) ? 1.0f : 0.0f;
        }
        const float inv1 = 1.0f / (0.4f + 1e-8f);
        const float inv2 = 1.0f / (0.8f + 1e-8f);
        const float inv3 = 1.0f / (1.2f + 1e-8f);
#pragma unroll
        for (int j = 0; j < 15; j++) {
            float tj = -3.2f + 0.4f * j;
            bb[j] = (x - tj) * inv1 * bb[j] + ((tj + 0.8f) - x) * inv1 * bb[j + 1];
        }
#pragma unroll
        for (int j = 0; j < 14; j++) {
            float tj = -3.2f + 0.4f * j;
            bb[j] = (x - tj) * inv2 * bb[j] + ((tj + 1.2f) - x) * inv2 * bb[j + 1];
        }
#pragma unroll
        for (int j = 0; j < 13; j++) {
            float tj = -3.2f + 0.4f * j;
            bb[j] = (x - tj) * inv3 * bb[j] + ((tj + 1.6f) - x) * inv3 * bb[j + 1];
        }
#pragma unroll
        for (int g = 0; g < NG; g++) rowbuf[IN_F + i * NG + g] = f2bf(bb[g]);
    }
    __syncthreads();

    const float4* src = (const float4*)rowbuf;          // coalesced writeback
    float4* dst = (float4*)(A + (long)b * K_TOT);
    for (int t = tid; t < K_TOT / 8; t += 256) dst[t] = src[t];
}

// ---------------- GEMM: m97 structure, split-K to partials ----------------
__global__ __launch_bounds__(256)
void kan_gemm(const unsigned short* __restrict__ A,   // [chunk][7168] bf16 bits
              const unsigned short* __restrict__ Wb,  // [512][7168]  bf16 bits
              const float* __restrict__ bias,         // [512]
              float* __restrict__ out,                // [8192][512] fp32
              float* __restrict__ part,               // [(ks-1)][chunk][512]
              int row0, int kiters, int chunk) {
    __shared__ unsigned short As[BM * BK];   // 16 KB, unpadded (gl_lds layout)
    __shared__ unsigned short Bs[BN * BK];   // 16 KB

    const int tid  = threadIdx.x;
    const int lane = tid & 63;
    const int wave = tid >> 6;
    const int wm   = wave >> 1;      // 0..1
    const int wn   = wave & 1;       // 0..1
    const int quad = lane >> 4;      // 0..3
    const int l16  = lane & 15;

    const int m0 = blockIdx.x * BM;          // row within chunk
    const int n0 = blockIdx.y * BN;
    const int ks = blockIdx.z;
    const long kbase = (long)ks * kiters * BK;

    // staging decode: instr q of wave w covers LDS rows w*32+q*8 .. +8
    // lane i -> row +(i>>3), col shorts (i&7)*8  (matches lane*16B contiguity)
    const int sr = lane >> 3;                // 0..7
    const int sc = (lane & 7) * 8;           // col in shorts

    const unsigned short* gA = A  + (long)(m0 + wave * 32 + sr) * K_TOT + kbase + sc;
    const unsigned short* gB = Wb + (long)(n0 + wave * 32 + sr) * K_TOT + kbase + sc;
    unsigned short* lA = As + (wave * 32 + sr * 0) * BK;   // wave-uniform base
    unsigned short* lB = Bs + (wave * 32) * BK;
    lA = As + (wave * 32) * BK;

    floatx4 acc[4][4];
#pragma unroll
    for (int i = 0; i < 4; i++)
#pragma unroll
        for (int j = 0; j < 4; j++) acc[i][j] = (floatx4){0.f, 0.f, 0.f, 0.f};

    for (int kk = 0; kk < kiters; kk++) {
        __syncthreads();                     // prior compute done before overwrite
#pragma unroll
        for (int q = 0; q < 4; q++) {
            gl2lds16(gA + (long)q * 8 * K_TOT, lA + q * 8 * BK);
            gl2lds16(gB + (long)q * 8 * K_TOT, lB + q * 8 * BK);
        }
        gA += BK; gB += BK;
        __syncthreads();                     // drains vmcnt (compiler-inserted)

#pragma unroll
        for (int s = 0; s < 2; s++) {        // two k=32 MFMA steps per BK=64
            short8 af[4], bf[4];
#pragma unroll
            for (int t = 0; t < 4; t++)
                af[t] = *(const short8*)(As + (wm * 64 + t * 16 + l16) * BK + s * 32 + quad * 8);
#pragma unroll
            for (int t = 0; t < 4; t++)
                bf[t] = *(const short8*)(Bs + (wn * 64 + t * 16 + l16) * BK + s * 32 + quad * 8);
#pragma unroll
            for (int i = 0; i < 4; i++)
#pragma unroll
                for (int j = 0; j < 4; j++)
                    acc[i][j] = __builtin_amdgcn_mfma_f32_16x16x32_bf16(
                        af[i], bf[j], acc[i][j], 0, 0, 0);
        }
    }

    // epilogue: C/D layout col=lane&15, row=quad*4+reg
    float* dst;
    long rstride = N_OUT;
    if (ks == 0) dst = out + (long)row0 * N_OUT;
    else         dst = part + (long)(ks - 1) * chunk * N_OUT;
#pragma unroll
    for (int i = 0; i < 4; i++) {
        int r0 = m0 + wm * 64 + i * 16 + quad * 4;
#pragma unroll
        for (int j = 0; j < 4; j++) {
            int col = n0 + wn * 64 + j * 16 + l16;
            float bv = (ks == 0) ? bias[col] : 0.0f;
#pragma unroll
            for (int r = 0; r < 4; r++)
                dst[(long)(r0 + r) * rstride + col] = acc[i][j][r] + bv;
        }
    }
}

// ---------------- partial reduction: out += sum(partials) ----------------
__global__ void kan_reduce(float* __restrict__ out,        // chunk*512 floats
                           const float* __restrict__ part, // [ns][chunk*512]
                           int ns, long n4) {              // n4 = chunk*512/4
    long t = (long)blockIdx.x * 256 + threadIdx.x;
    if (t >= n4) return;
    float4 v = ((const float4*)out)[t];
    for (int s = 0; s < ns; s++) {
        float4 p = ((const float4*)part)[s * n4 + t];
        v.x += p.x; v.y += p.y; v.z += p.z; v.w += p.w;
    }
    ((float4*)out)[t] = v;
}

extern "C" void kernel_launch(void* const* d_in, const int* in_sizes, int n_in,
                              void* d_out, int out_size, void* d_ws, size_t ws_size,
                              hipStream_t stream) {
    const float* x        = (const float*)d_in[0];
    const float* base_w   = (const float*)d_in[1];
    const float* base_b   = (const float*)d_in[2];
    const float* spline_w = (const float*)d_in[3];
    float* out = (float*)d_out;

    unsigned short* Wb = (unsigned short*)d_ws;            // 512*7168 bf16
    const size_t wbytes = (size_t)N_OUT * K_TOT * 2;       // 7.34 MB

    // pick largest chunk (then largest ksplit) that fits ws:
    //   ws = Wb + A[chunk][7168] bf16 + partials (ksplit-1)*chunk*512 fp32
    int chunk = BATCH, ksplit = KSMAX;
    while (chunk > 128 &&
           wbytes + (size_t)chunk * K_TOT * 2 +
           (size_t)(KSMAX - 1) * chunk * N_OUT * 4 > ws_size) chunk >>= 1;
    while (ksplit > 1 &&
           wbytes + (size_t)chunk * K_TOT * 2 +
           (size_t)(ksplit - 1) * chunk * N_OUT * 4 > ws_size) ksplit--;

    unsigned short* Abuf = Wb + (size_t)N_OUT * K_TOT;
    float* part = (float*)(Abuf + (size_t)chunk * K_TOT);
    const int kiters = (K_TOT / BK) / ksplit;              // 112/ks, exact

    kan_wconv<<<dim3(K_TOT / 256, N_OUT), 256, 0, stream>>>(base_w, spline_w, Wb);

    for (int row0 = 0; row0 < BATCH; row0 += chunk) {
        kan_prep<<<dim3(chunk), 256, 0, stream>>>(x, Abuf, row0);
        kan_gemm<<<dim3(chunk / BM, N_OUT / BN, ksplit), 256, 0, stream>>>(
            Abuf, Wb, base_b, out, part, row0, kiters, chunk);
        if (ksplit > 1) {
            long n4 = (long)chunk * N_OUT / 4;
            kan_reduce<<<dim3((n4 + 255) / 256), 256, 0, stream>>>(
                out + (long)row0 * N_OUT, part, ksplit - 1, n4);
        }
    }
}

// Round 4
// 205.356 us; speedup vs baseline: 2.3158x; 1.0406x over previous
//
#include <hip/hip_runtime.h>
#include <hip/hip_bf16.h>

// KAN layer as one bf16 GEMM: out[8192,512] = A[8192,7168] @ W[512,7168]^T + b
// A layout is BASIS-MAJOR: col k = plane*512 + i, plane 0 = silu(x_i),
// planes 1..13 = b-spline bases g=0..12 of x_i. W permuted to match.
// R3: m97-style GEMM (global_load_lds w16, 128x128 tile) + split-K partials.
// R4: prep rewritten — no LDS, __expf, coalesced ushort2 stores to
//     basis-major planes (R3 prep was ~75us vs 21us traffic floor: precise
//     expf + scattered ds_write_b16 + pointless LDS round trip).

#define BATCH   8192
#define IN_F    512
#define N_OUT   512
#define NG      13            // GRID_SIZE + K
#define NPL     14            // planes: silu + 13 bases
#define K_TOT   7168          // 14 * 512
#define BM      128
#define BN      128
#define BK      64
#define KSMAX   4

typedef short short8 __attribute__((ext_vector_type(8)));
typedef float floatx4 __attribute__((ext_vector_type(4)));

__device__ __forceinline__ unsigned short f2bf(float f) {
    union { float f; unsigned u; } v; v.f = f;
    unsigned r = v.u + 0x7FFFu + ((v.u >> 16) & 1u);   // RNE
    return (unsigned short)(r >> 16);
}

__device__ __forceinline__ void gl2lds16(const unsigned short* g, unsigned short* l) {
    __builtin_amdgcn_global_load_lds(
        (const __attribute__((address_space(1))) unsigned int*)g,
        (__attribute__((address_space(3))) unsigned int*)l, 16, 0, 0);
}

// ---------------- W conversion: Wb[o][plane*512 + i] ----------------
__global__ void kan_wconv(const float* __restrict__ base_w,
                          const float* __restrict__ spline_w,
                          unsigned short* __restrict__ Wb) {
    int c = blockIdx.x * 256 + threadIdx.x;   // 0..7167  (grid.x = 28)
    int o = blockIdx.y;                        // 0..511
    int pl = c >> 9;                           // plane
    int i  = c & 511;
    float v = (pl == 0) ? base_w[o * IN_F + i]
                        : spline_w[(long)o * (IN_F * NG) + i * NG + (pl - 1)];
    Wb[(long)o * K_TOT + c] = f2bf(v);
}

// ---------------- A construction: silu + cubic B-spline bases ----------------
// One thread per (row, feature-pair). All 14 stores are coalesced ushort2.
__global__ __launch_bounds__(256)
void kan_prep(const float* __restrict__ X,
              unsigned short* __restrict__ A,
              int row0) {
    const int b  = blockIdx.x;
    const int ip = threadIdx.x;                // feature pair 0..255
    float2 x2 = ((const float2*)(X + (long)(row0 + b) * IN_F))[ip];

    float outv[2][NPL];
#pragma unroll
    for (int e = 0; e < 2; e++) {
        float x = (e == 0) ? x2.x : x2.y;
        // silu via fast exp + hw rcp (bf16 output swamps the approx error)
        outv[e][0] = x * __builtin_amdgcn_rcpf(1.0f + __expf(-x));

        // cubic Cox-de Boor on uniform knots t_j = -3.2 + 0.4j
        float bb[16];
#pragma unroll
        for (int j = 0; j < 16; j++) {
            float t0 = -3.2f + 0.4f * j;
            bb[j] = (x >= t0 && x < t0 + 0.4f) ? 1.0f : 0.0f;
        }
        const float inv1 = 1.0f / (0.4f + 1e-8f);
        const float inv2 = 1.0f / (0.8f + 1e-8f);
        const float inv3 = 1.0f / (1.2f + 1e-8f);
#pragma unroll
        for (int j = 0; j < 15; j++) {
            float tj = -3.2f + 0.4f * j;
            bb[j] = (x - tj) * inv1 * bb[j] + ((tj + 0.8f) - x) * inv1 * bb[j + 1];
        }
#pragma unroll
        for (int j = 0; j < 14; j++) {
            float tj = -3.2f + 0.4f * j;
            bb[j] = (x - tj) * inv2 * bb[j] + ((tj + 1.2f) - x) * inv2 * bb[j + 1];
        }
#pragma unroll
        for (int j = 0; j < 13; j++) {
            float tj = -3.2f + 0.4f * j;
            bb[j] = (x - tj) * inv3 * bb[j] + ((tj + 1.6f) - x) * inv3 * bb[j + 1];
        }
#pragma unroll
        for (int g = 0; g < NG; g++) outv[e][1 + g] = bb[g];
    }

    unsigned short* arow = A + (long)b * K_TOT + ip * 2;
#pragma unroll
    for (int pl = 0; pl < NPL; pl++) {
        unsigned int pk = (unsigned int)f2bf(outv[0][pl]) |
                          ((unsigned int)f2bf(outv[1][pl]) << 16);
        *(unsigned int*)(arow + pl * IN_F) = pk;
    }
}

// ---------------- GEMM: m97 structure, split-K to partials ----------------
__global__ __launch_bounds__(256)
void kan_gemm(const unsigned short* __restrict__ A,   // [chunk][7168] bf16 bits
              const unsigned short* __restrict__ Wb,  // [512][7168]  bf16 bits
              const float* __restrict__ bias,         // [512]
              float* __restrict__ out,                // [8192][512] fp32
              float* __restrict__ part,               // [(ks-1)][chunk][512]
              int row0, int kiters, int chunk) {
    __shared__ unsigned short As[BM * BK];   // 16 KB, unpadded (gl_lds layout)
    __shared__ unsigned short Bs[BN * BK];   // 16 KB

    const int tid  = threadIdx.x;
    const int lane = tid & 63;
    const int wave = tid >> 6;
    const int wm   = wave >> 1;      // 0..1
    const int wn   = wave & 1;       // 0..1
    const int quad = lane >> 4;      // 0..3
    const int l16  = lane & 15;

    const int m0 = blockIdx.x * BM;          // row within chunk
    const int n0 = blockIdx.y * BN;
    const int ks = blockIdx.z;
    const long kbase = (long)ks * kiters * BK;

    // staging: lane i of wave w -> LDS row w*32+(i>>3), col shorts (i&7)*8
    const int sr = lane >> 3;                // 0..7
    const int sc = (lane & 7) * 8;           // col in shorts

    const unsigned short* gA = A  + (long)(m0 + wave * 32 + sr) * K_TOT + kbase + sc;
    const unsigned short* gB = Wb + (long)(n0 + wave * 32 + sr) * K_TOT + kbase + sc;
    unsigned short* lA = As + (wave * 32) * BK;   // wave-uniform base
    unsigned short* lB = Bs + (wave * 32) * BK;

    floatx4 acc[4][4];
#pragma unroll
    for (int i = 0; i < 4; i++)
#pragma unroll
        for (int j = 0; j < 4; j++) acc[i][j] = (floatx4){0.f, 0.f, 0.f, 0.f};

    for (int kk = 0; kk < kiters; kk++) {
        __syncthreads();                     // prior compute done before overwrite
#pragma unroll
        for (int q = 0; q < 4; q++) {
            gl2lds16(gA + (long)q * 8 * K_TOT, lA + q * 8 * BK);
            gl2lds16(gB + (long)q * 8 * K_TOT, lB + q * 8 * BK);
        }
        gA += BK; gB += BK;
        __syncthreads();                     // drains vmcnt (compiler-inserted)

#pragma unroll
        for (int s = 0; s < 2; s++) {        // two k=32 MFMA steps per BK=64
            short8 af[4], bf[4];
#pragma unroll
            for (int t = 0; t < 4; t++)
                af[t] = *(const short8*)(As + (wm * 64 + t * 16 + l16) * BK + s * 32 + quad * 8);
#pragma unroll
            for (int t = 0; t < 4; t++)
                bf[t] = *(const short8*)(Bs + (wn * 64 + t * 16 + l16) * BK + s * 32 + quad * 8);
#pragma unroll
            for (int i = 0; i < 4; i++)
#pragma unroll
                for (int j = 0; j < 4; j++)
                    acc[i][j] = __builtin_amdgcn_mfma_f32_16x16x32_bf16(
                        af[i], bf[j], acc[i][j], 0, 0, 0);
        }
    }

    // epilogue: C/D layout col=lane&15, row=quad*4+reg
    float* dst;
    if (ks == 0) dst = out + (long)row0 * N_OUT;
    else         dst = part + (long)(ks - 1) * chunk * N_OUT;
#pragma unroll
    for (int i = 0; i < 4; i++) {
        int r0 = m0 + wm * 64 + i * 16 + quad * 4;
#pragma unroll
        for (int j = 0; j < 4; j++) {
            int col = n0 + wn * 64 + j * 16 + l16;
            float bv = (ks == 0) ? bias[col] : 0.0f;
#pragma unroll
            for (int r = 0; r < 4; r++)
                dst[(long)(r0 + r) * N_OUT + col] = acc[i][j][r] + bv;
        }
    }
}

// ---------------- partial reduction: out += sum(partials) ----------------
__global__ void kan_reduce(float* __restrict__ out,        // chunk*512 floats
                           const float* __restrict__ part, // [ns][chunk*512]
                           int ns, long n4) {              // n4 = chunk*512/4
    long t = (long)blockIdx.x * 256 + threadIdx.x;
    if (t >= n4) return;
    float4 v = ((const float4*)out)[t];
    for (int s = 0; s < ns; s++) {
        float4 p = ((const float4*)part)[s * n4 + t];
        v.x += p.x; v.y += p.y; v.z += p.z; v.w += p.w;
    }
    ((float4*)out)[t] = v;
}

extern "C" void kernel_launch(void* const* d_in, const int* in_sizes, int n_in,
                              void* d_out, int out_size, void* d_ws, size_t ws_size,
                              hipStream_t stream) {
    const float* x        = (const float*)d_in[0];
    const float* base_w   = (const float*)d_in[1];
    const float* base_b   = (const float*)d_in[2];
    const float* spline_w = (const float*)d_in[3];
    float* out = (float*)d_out;

    unsigned short* Wb = (unsigned short*)d_ws;            // 512*7168 bf16
    const size_t wbytes = (size_t)N_OUT * K_TOT * 2;       // 7.34 MB

    // pick largest chunk (then largest ksplit) that fits ws:
    //   ws = Wb + A[chunk][7168] bf16 + partials (ksplit-1)*chunk*512 fp32
    int chunk = BATCH, ksplit = KSMAX;
    while (chunk > 128 &&
           wbytes + (size_t)chunk * K_TOT * 2 +
           (size_t)(KSMAX - 1) * chunk * N_OUT * 4 > ws_size) chunk >>= 1;
    while (ksplit > 1 &&
           wbytes + (size_t)chunk * K_TOT * 2 +
           (size_t)(ksplit - 1) * chunk * N_OUT * 4 > ws_size) ksplit--;

    unsigned short* Abuf = Wb + (size_t)N_OUT * K_TOT;
    float* part = (float*)(Abuf + (size_t)chunk * K_TOT);
    const int kiters = (K_TOT / BK) / ksplit;              // 112/ks, exact

    kan_wconv<<<dim3(K_TOT / 256, N_OUT), 256, 0, stream>>>(base_w, spline_w, Wb);

    for (int row0 = 0; row0 < BATCH; row0 += chunk) {
        kan_prep<<<dim3(chunk), 256, 0, stream>>>(x, Abuf, row0);
        kan_gemm<<<dim3(chunk / BM, N_OUT / BN, ksplit), 256, 0, stream>>>(
            Abuf, Wb, base_b, out, part, row0, kiters, chunk);
        if (ksplit > 1) {
            long n4 = (long)chunk * N_OUT / 4;
            kan_reduce<<<dim3((n4 + 255) / 256), 256, 0, stream>>>(
                out + (long)row0 * N_OUT, part, ksplit - 1, n4);
        }
    }
}

// Round 5
// 198.863 us; speedup vs baseline: 2.3914x; 1.0326x over previous
//
#include <hip/hip_runtime.h>
#include <hip/hip_bf16.h>

// KAN layer as one bf16 GEMM: out[8192,512] = A[8192,7168] @ W[512,7168]^T + b
// A layout is BASIS-MAJOR: col k = plane*512 + i, plane 0 = silu(x_i),
// planes 1..13 = b-spline bases g=0..12 of x_i. W permuted to match.
// R3: m97-style GEMM (global_load_lds w16, 128x128 tile) + split-K partials.
// R4: prep rewritten — register-only, __expf, coalesced ushort2 plane stores.
// R5: LDS XOR bank swizzle. R4 profile: SQ_LDS_BANK_CONFLICT=2.2e7 per gemm
//     (~12 cyc per ds_read_b128, ~36% of runtime) because fragment reads at
//     R*128 + (4s+quad)*16 put 16 lanes of a quad on the same 4 banks.
//     global_load_lds has per-lane GLOBAL addresses, so lane (r=l>>3,c=l&7)
//     fetches global chunk c^r; reads use col ((4s+quad)^(lane&7))*16 ->
//     2 lanes/bank (free). Coalescing unchanged (permuted within 128B rows).

#define BATCH   8192
#define IN_F    512
#define N_OUT   512
#define NG      13            // GRID_SIZE + K
#define NPL     14            // planes: silu + 13 bases
#define K_TOT   7168          // 14 * 512
#define BM      128
#define BN      128
#define BK      64
#define KSMAX   4

typedef short short8 __attribute__((ext_vector_type(8)));
typedef float floatx4 __attribute__((ext_vector_type(4)));

__device__ __forceinline__ unsigned short f2bf(float f) {
    union { float f; unsigned u; } v; v.f = f;
    unsigned r = v.u + 0x7FFFu + ((v.u >> 16) & 1u);   // RNE
    return (unsigned short)(r >> 16);
}

__device__ __forceinline__ void gl2lds16(const unsigned short* g, unsigned short* l) {
    __builtin_amdgcn_global_load_lds(
        (const __attribute__((address_space(1))) unsigned int*)g,
        (__attribute__((address_space(3))) unsigned int*)l, 16, 0, 0);
}

// ---------------- W conversion: Wb[o][plane*512 + i] ----------------
__global__ void kan_wconv(const float* __restrict__ base_w,
                          const float* __restrict__ spline_w,
                          unsigned short* __restrict__ Wb) {
    int c = blockIdx.x * 256 + threadIdx.x;   // 0..7167  (grid.x = 28)
    int o = blockIdx.y;                        // 0..511
    int pl = c >> 9;                           // plane
    int i  = c & 511;
    float v = (pl == 0) ? base_w[o * IN_F + i]
                        : spline_w[(long)o * (IN_F * NG) + i * NG + (pl - 1)];
    Wb[(long)o * K_TOT + c] = f2bf(v);
}

// ---------------- A construction: silu + cubic B-spline bases ----------------
__global__ __launch_bounds__(256)
void kan_prep(const float* __restrict__ X,
              unsigned short* __restrict__ A,
              int row0) {
    const int b  = blockIdx.x;
    const int ip = threadIdx.x;                // feature pair 0..255
    float2 x2 = ((const float2*)(X + (long)(row0 + b) * IN_F))[ip];

    float outv[2][NPL];
#pragma unroll
    for (int e = 0; e < 2; e++) {
        float x = (e == 0) ? x2.x : x2.y;
        outv[e][0] = x * __builtin_amdgcn_rcpf(1.0f + __expf(-x));  // silu

        // cubic Cox-de Boor on uniform knots t_j = -3.2 + 0.4j
        float bb[16];
#pragma unroll
        for (int j = 0; j < 16; j++) {
            float t0 = -3.2f + 0.4f * j;
            bb[j] = (x >= t0 && x < t0 + 0.4f) ? 1.0f : 0.0f;
        }
        const float inv1 = 1.0f / (0.4f + 1e-8f);
        const float inv2 = 1.0f / (0.8f + 1e-8f);
        const float inv3 = 1.0f / (1.2f + 1e-8f);
#pragma unroll
        for (int j = 0; j < 15; j++) {
            float tj = -3.2f + 0.4f * j;
            bb[j] = (x - tj) * inv1 * bb[j] + ((tj + 0.8f) - x) * inv1 * bb[j + 1];
        }
#pragma unroll
        for (int j = 0; j < 14; j++) {
            float tj = -3.2f + 0.4f * j;
            bb[j] = (x - tj) * inv2 * bb[j] + ((tj + 1.2f) - x) * inv2 * bb[j + 1];
        }
#pragma unroll
        for (int j = 0; j < 13; j++) {
            float tj = -3.2f + 0.4f * j;
            bb[j] = (x - tj) * inv3 * bb[j] + ((tj + 1.6f) - x) * inv3 * bb[j + 1];
        }
#pragma unroll
        for (int g = 0; g < NG; g++) outv[e][1 + g] = bb[g];
    }

    unsigned short* arow = A + (long)b * K_TOT + ip * 2;
#pragma unroll
    for (int pl = 0; pl < NPL; pl++) {
        unsigned int pk = (unsigned int)f2bf(outv[0][pl]) |
                          ((unsigned int)f2bf(outv[1][pl]) << 16);
        *(unsigned int*)(arow + pl * IN_F) = pk;
    }
}

// ---------------- GEMM: m97 structure + XOR swizzle, split-K partials ----------------
__global__ __launch_bounds__(256)
void kan_gemm(const unsigned short* __restrict__ A,   // [chunk][7168] bf16 bits
              const unsigned short* __restrict__ Wb,  // [512][7168]  bf16 bits
              const float* __restrict__ bias,         // [512]
              float* __restrict__ out,                // [8192][512] fp32
              float* __restrict__ part,               // [(ks-1)][chunk][512]
              int row0, int kiters, int chunk) {
    __shared__ unsigned short As[BM * BK];   // 16 KB; swizzled layout:
    __shared__ unsigned short Bs[BN * BK];   // row R, 16B-chunk J at pos J^(R&7)

    const int tid  = threadIdx.x;
    const int lane = tid & 63;
    const int wave = tid >> 6;
    const int wm   = wave >> 1;      // 0..1
    const int wn   = wave & 1;       // 0..1
    const int quad = lane >> 4;      // 0..3
    const int l16  = lane & 15;
    const int x7   = lane & 7;       // swizzle key for fragment reads

    const int m0 = blockIdx.x * BM;          // row within chunk
    const int n0 = blockIdx.y * BN;
    const int ks = blockIdx.z;
    const long kbase = (long)ks * kiters * BK;

    // staging: lane l of wave w -> LDS row w*32+(l>>3), chunk c=l&7.
    // XOR swizzle: fetch GLOBAL chunk c^r so LDS pos p holds global chunk p^r.
    const int sr  = lane >> 3;               // 0..7
    const int scs = ((lane & 7) ^ sr) * 8;   // swizzled col in shorts

    const unsigned short* gA = A  + (long)(m0 + wave * 32 + sr) * K_TOT + kbase + scs;
    const unsigned short* gB = Wb + (long)(n0 + wave * 32 + sr) * K_TOT + kbase + scs;
    unsigned short* lA = As + (wave * 32) * BK;   // wave-uniform base
    unsigned short* lB = Bs + (wave * 32) * BK;

    floatx4 acc[4][4];
#pragma unroll
    for (int i = 0; i < 4; i++)
#pragma unroll
        for (int j = 0; j < 4; j++) acc[i][j] = (floatx4){0.f, 0.f, 0.f, 0.f};

    for (int kk = 0; kk < kiters; kk++) {
        __syncthreads();                     // prior compute done before overwrite
#pragma unroll
        for (int q = 0; q < 4; q++) {
            gl2lds16(gA + (long)q * 8 * K_TOT, lA + q * 8 * BK);
            gl2lds16(gB + (long)q * 8 * K_TOT, lB + q * 8 * BK);
        }
        gA += BK; gB += BK;
        __syncthreads();                     // drains vmcnt (compiler-inserted)

#pragma unroll
        for (int s = 0; s < 2; s++) {        // two k=32 MFMA steps per BK=64
            const int cofs = ((4 * s + quad) ^ x7) * 8;   // swizzled read col
            short8 af[4], bf[4];
#pragma unroll
            for (int t = 0; t < 4; t++)
                af[t] = *(const short8*)(As + (wm * 64 + t * 16 + l16) * BK + cofs);
#pragma unroll
            for (int t = 0; t < 4; t++)
                bf[t] = *(const short8*)(Bs + (wn * 64 + t * 16 + l16) * BK + cofs);
#pragma unroll
            for (int i = 0; i < 4; i++)
#pragma unroll
                for (int j = 0; j < 4; j++)
                    acc[i][j] = __builtin_amdgcn_mfma_f32_16x16x32_bf16(
                        af[i], bf[j], acc[i][j], 0, 0, 0);
        }
    }

    // epilogue: C/D layout col=lane&15, row=quad*4+reg
    float* dst;
    if (ks == 0) dst = out + (long)row0 * N_OUT;
    else         dst = part + (long)(ks - 1) * chunk * N_OUT;
#pragma unroll
    for (int i = 0; i < 4; i++) {
        int r0 = m0 + wm * 64 + i * 16 + quad * 4;
#pragma unroll
        for (int j = 0; j < 4; j++) {
            int col = n0 + wn * 64 + j * 16 + l16;
            float bv = (ks == 0) ? bias[col] : 0.0f;
#pragma unroll
            for (int r = 0; r < 4; r++)
                dst[(long)(r0 + r) * N_OUT + col] = acc[i][j][r] + bv;
        }
    }
}

// ---------------- partial reduction: out += sum(partials) ----------------
__global__ void kan_reduce(float* __restrict__ out,        // chunk*512 floats
                           const float* __restrict__ part, // [ns][chunk*512]
                           int ns, long n4) {              // n4 = chunk*512/4
    long t = (long)blockIdx.x * 256 + threadIdx.x;
    if (t >= n4) return;
    float4 v = ((const float4*)out)[t];
    for (int s = 0; s < ns; s++) {
        float4 p = ((const float4*)part)[s * n4 + t];
        v.x += p.x; v.y += p.y; v.z += p.z; v.w += p.w;
    }
    ((float4*)out)[t] = v;
}

extern "C" void kernel_launch(void* const* d_in, const int* in_sizes, int n_in,
                              void* d_out, int out_size, void* d_ws, size_t ws_size,
                              hipStream_t stream) {
    const float* x        = (const float*)d_in[0];
    const float* base_w   = (const float*)d_in[1];
    const float* base_b   = (const float*)d_in[2];
    const float* spline_w = (const float*)d_in[3];
    float* out = (float*)d_out;

    unsigned short* Wb = (unsigned short*)d_ws;            // 512*7168 bf16
    const size_t wbytes = (size_t)N_OUT * K_TOT * 2;       // 7.34 MB

    // pick largest chunk (then largest ksplit) that fits ws:
    //   ws = Wb + A[chunk][7168] bf16 + partials (ksplit-1)*chunk*512 fp32
    int chunk = BATCH, ksplit = KSMAX;
    while (chunk > 128 &&
           wbytes + (size_t)chunk * K_TOT * 2 +
           (size_t)(KSMAX - 1) * chunk * N_OUT * 4 > ws_size) chunk >>= 1;
    while (ksplit > 1 &&
           wbytes + (size_t)chunk * K_TOT * 2 +
           (size_t)(ksplit - 1) * chunk * N_OUT * 4 > ws_size) ksplit--;

    unsigned short* Abuf = Wb + (size_t)N_OUT * K_TOT;
    float* part = (float*)(Abuf + (size_t)chunk * K_TOT);
    const int kiters = (K_TOT / BK) / ksplit;              // 112/ks, exact

    kan_wconv<<<dim3(K_TOT / 256, N_OUT), 256, 0, stream>>>(base_w, spline_w, Wb);

    for (int row0 = 0; row0 < BATCH; row0 += chunk) {
        kan_prep<<<dim3(chunk), 256, 0, stream>>>(x, Abuf, row0);
        kan_gemm<<<dim3(chunk / BM, N_OUT / BN, ksplit), 256, 0, stream>>>(
            Abuf, Wb, base_b, out, part, row0, kiters, chunk);
        if (ksplit > 1) {
            long n4 = (long)chunk * N_OUT / 4;
            kan_reduce<<<dim3((n4 + 255) / 256), 256, 0, stream>>>(
                out + (long)row0 * N_OUT, part, ksplit - 1, n4);
        }
    }
}

// Round 6
// 190.488 us; speedup vs baseline: 2.4966x; 1.0440x over previous
//
#include <hip/hip_runtime.h>
#include <hip/hip_bf16.h>

// KAN layer as one bf16 GEMM: out[8192,512] = A[8192,7168] @ W[512,7168]^T + b
// A layout is BASIS-MAJOR: col k = plane*512 + i, plane 0 = silu(x_i),
// planes 1..13 = b-spline bases g=0..12 of x_i. W permuted to match.
// R3: m97-style GEMM (global_load_lds w16, 128x128 tile) + split-K partials.
// R4: prep rewritten — register-only, __expf, coalesced ushort2 plane stores.
// R5: LDS XOR bank swizzle (chunk J of row R at pos J^(R&7)) -> conflicts 2.2e7 -> 0.
// R6: 32x32x16 MFMA (half the instructions, 2495 vs 2176 TF pipe rate) to cut
//     issue-slot contention with staging VALU; bf16 split-K partials (gemm
//     WRITE 65->42 MB, reduce 84->59 MB).

#define BATCH   8192
#define IN_F    512
#define N_OUT   512
#define NG      13            // GRID_SIZE + K
#define NPL     14            // planes: silu + 13 bases
#define K_TOT   7168          // 14 * 512
#define BM      128
#define BN      128
#define BK      64
#define KSMAX   4

typedef short short8 __attribute__((ext_vector_type(8)));
typedef float floatx16 __attribute__((ext_vector_type(16)));

__device__ __forceinline__ unsigned short f2bf(float f) {
    union { float f; unsigned u; } v; v.f = f;
    unsigned r = v.u + 0x7FFFu + ((v.u >> 16) & 1u);   // RNE
    return (unsigned short)(r >> 16);
}
__device__ __forceinline__ float bf2f(unsigned short h) {
    union { unsigned u; float f; } v; v.u = (unsigned)h << 16;
    return v.f;
}

__device__ __forceinline__ void gl2lds16(const unsigned short* g, unsigned short* l) {
    __builtin_amdgcn_global_load_lds(
        (const __attribute__((address_space(1))) unsigned int*)g,
        (__attribute__((address_space(3))) unsigned int*)l, 16, 0, 0);
}

// ---------------- W conversion: Wb[o][plane*512 + i] ----------------
__global__ void kan_wconv(const float* __restrict__ base_w,
                          const float* __restrict__ spline_w,
                          unsigned short* __restrict__ Wb) {
    int c = blockIdx.x * 256 + threadIdx.x;   // 0..7167  (grid.x = 28)
    int o = blockIdx.y;                        // 0..511
    int pl = c >> 9;                           // plane
    int i  = c & 511;
    float v = (pl == 0) ? base_w[o * IN_F + i]
                        : spline_w[(long)o * (IN_F * NG) + i * NG + (pl - 1)];
    Wb[(long)o * K_TOT + c] = f2bf(v);
}

// ---------------- A construction: silu + cubic B-spline bases ----------------
__global__ __launch_bounds__(256)
void kan_prep(const float* __restrict__ X,
              unsigned short* __restrict__ A,
              int row0) {
    const int b  = blockIdx.x;
    const int ip = threadIdx.x;                // feature pair 0..255
    float2 x2 = ((const float2*)(X + (long)(row0 + b) * IN_F))[ip];

    float outv[2][NPL];
#pragma unroll
    for (int e = 0; e < 2; e++) {
        float x = (e == 0) ? x2.x : x2.y;
        outv[e][0] = x * __builtin_amdgcn_rcpf(1.0f + __expf(-x));  // silu

        // cubic Cox-de Boor on uniform knots t_j = -3.2 + 0.4j
        float bb[16];
#pragma unroll
        for (int j = 0; j < 16; j++) {
            float t0 = -3.2f + 0.4f * j;
            bb[j] = (x >= t0 && x < t0 + 0.4f) ? 1.0f : 0.0f;
        }
        const float inv1 = 1.0f / (0.4f + 1e-8f);
        const float inv2 = 1.0f / (0.8f + 1e-8f);
        const float inv3 = 1.0f / (1.2f + 1e-8f);
#pragma unroll
        for (int j = 0; j < 15; j++) {
            float tj = -3.2f + 0.4f * j;
            bb[j] = (x - tj) * inv1 * bb[j] + ((tj + 0.8f) - x) * inv1 * bb[j + 1];
        }
#pragma unroll
        for (int j = 0; j < 14; j++) {
            float tj = -3.2f + 0.4f * j;
            bb[j] = (x - tj) * inv2 * bb[j] + ((tj + 1.2f) - x) * inv2 * bb[j + 1];
        }
#pragma unroll
        for (int j = 0; j < 13; j++) {
            float tj = -3.2f + 0.4f * j;
            bb[j] = (x - tj) * inv3 * bb[j] + ((tj + 1.6f) - x) * inv3 * bb[j + 1];
        }
#pragma unroll
        for (int g = 0; g < NG; g++) outv[e][1 + g] = bb[g];
    }

    unsigned short* arow = A + (long)b * K_TOT + ip * 2;
#pragma unroll
    for (int pl = 0; pl < NPL; pl++) {
        unsigned int pk = (unsigned int)f2bf(outv[0][pl]) |
                          ((unsigned int)f2bf(outv[1][pl]) << 16);
        *(unsigned int*)(arow + pl * IN_F) = pk;
    }
}

// ---------------- GEMM: m97 structure + swizzle, 32x32x16 MFMA ----------------
__global__ __launch_bounds__(256)
void kan_gemm(const unsigned short* __restrict__ A,   // [chunk][7168] bf16 bits
              const unsigned short* __restrict__ Wb,  // [512][7168]  bf16 bits
              const float* __restrict__ bias,         // [512]
              float* __restrict__ out,                // [8192][512] fp32
              unsigned short* __restrict__ part,      // [(ks-1)][chunk][512] bf16
              int row0, int kiters, int chunk) {
    __shared__ unsigned short As[BM * BK];   // 16 KB; swizzled layout:
    __shared__ unsigned short Bs[BN * BK];   // row R, 16B-chunk J at pos J^(R&7)

    const int lane = threadIdx.x & 63;
    const int wave = threadIdx.x >> 6;
    const int wm   = wave >> 1;      // 0..1
    const int wn   = wave & 1;       // 0..1
    const int l32  = lane & 31;      // mfma 32x32 row/col index
    const int hi   = lane >> 5;      // mfma k-half
    const int x7   = lane & 7;       // swizzle key (l32&7 == lane&7)

    const int m0 = blockIdx.x * BM;          // row within chunk
    const int n0 = blockIdx.y * BN;
    const int ks = blockIdx.z;
    const long kbase = (long)ks * kiters * BK;

    // staging: lane l of wave w -> LDS row w*32+(l>>3), chunk c=l&7.
    // XOR swizzle: fetch GLOBAL chunk c^r so LDS pos p holds global chunk p^r.
    const int sr  = lane >> 3;               // 0..7
    const int scs = ((lane & 7) ^ sr) * 8;   // swizzled col in shorts

    const unsigned short* gA = A  + (long)(m0 + wave * 32 + sr) * K_TOT + kbase + scs;
    const unsigned short* gB = Wb + (long)(n0 + wave * 32 + sr) * K_TOT + kbase + scs;
    unsigned short* lA = As + (wave * 32) * BK;   // wave-uniform base
    unsigned short* lB = Bs + (wave * 32) * BK;

    floatx16 acc[2][2];
#pragma unroll
    for (int i = 0; i < 2; i++)
#pragma unroll
        for (int j = 0; j < 2; j++)
#pragma unroll
            for (int r = 0; r < 16; r++) acc[i][j][r] = 0.0f;

    for (int kk = 0; kk < kiters; kk++) {
        __syncthreads();                     // prior compute done before overwrite
#pragma unroll
        for (int q = 0; q < 4; q++) {
            gl2lds16(gA + (long)q * 8 * K_TOT, lA + q * 8 * BK);
            gl2lds16(gB + (long)q * 8 * K_TOT, lB + q * 8 * BK);
        }
        gA += BK; gB += BK;
        __syncthreads();                     // drains vmcnt (compiler-inserted)

#pragma unroll
        for (int s = 0; s < 4; s++) {        // four k=16 MFMA steps per BK=64
            const int cofs = ((2 * s + hi) ^ x7) * 8;   // swizzled read col
            short8 af[2], bf[2];
#pragma unroll
            for (int t = 0; t < 2; t++)
                af[t] = *(const short8*)(As + (wm * 64 + t * 32 + l32) * BK + cofs);
#pragma unroll
            for (int t = 0; t < 2; t++)
                bf[t] = *(const short8*)(Bs + (wn * 64 + t * 32 + l32) * BK + cofs);
#pragma unroll
            for (int i = 0; i < 2; i++)
#pragma unroll
                for (int j = 0; j < 2; j++)
                    acc[i][j] = __builtin_amdgcn_mfma_f32_32x32x16_bf16(
                        af[i], bf[j], acc[i][j], 0, 0, 0);
        }
    }

    // epilogue: 32x32 C/D layout col=lane&31, row=(reg&3)+8*(reg>>2)+4*hi
    if (ks == 0) {
        float* dst = out + (long)row0 * N_OUT;
#pragma unroll
        for (int i = 0; i < 2; i++) {
            int r0 = m0 + wm * 64 + i * 32 + 4 * hi;
#pragma unroll
            for (int j = 0; j < 2; j++) {
                int col = n0 + wn * 64 + j * 32 + l32;
                float bv = bias[col];
#pragma unroll
                for (int reg = 0; reg < 16; reg++) {
                    int row = r0 + (reg & 3) + 8 * (reg >> 2);
                    dst[(long)row * N_OUT + col] = acc[i][j][reg] + bv;
                }
            }
        }
    } else {
        unsigned short* dst = part + (long)(ks - 1) * chunk * N_OUT;
#pragma unroll
        for (int i = 0; i < 2; i++) {
            int r0 = m0 + wm * 64 + i * 32 + 4 * hi;
#pragma unroll
            for (int j = 0; j < 2; j++) {
                int col = n0 + wn * 64 + j * 32 + l32;
#pragma unroll
                for (int reg = 0; reg < 16; reg++) {
                    int row = r0 + (reg & 3) + 8 * (reg >> 2);
                    dst[(long)row * N_OUT + col] = f2bf(acc[i][j][reg]);
                }
            }
        }
    }
}

// ---------------- partial reduction: out += sum(bf16 partials) ----------------
__global__ void kan_reduce(float* __restrict__ out,               // chunk*512 fp32
                           const unsigned short* __restrict__ part,
                           int ns, long n4) {                     // n4 = chunk*512/4
    long t = (long)blockIdx.x * 256 + threadIdx.x;
    if (t >= n4) return;
    float4 v = ((const float4*)out)[t];
    for (int s = 0; s < ns; s++) {
        ushort4 p = ((const ushort4*)part)[s * n4 + t];
        v.x += bf2f(p.x); v.y += bf2f(p.y); v.z += bf2f(p.z); v.w += bf2f(p.w);
    }
    ((float4*)out)[t] = v;
}

extern "C" void kernel_launch(void* const* d_in, const int* in_sizes, int n_in,
                              void* d_out, int out_size, void* d_ws, size_t ws_size,
                              hipStream_t stream) {
    const float* x        = (const float*)d_in[0];
    const float* base_w   = (const float*)d_in[1];
    const float* base_b   = (const float*)d_in[2];
    const float* spline_w = (const float*)d_in[3];
    float* out = (float*)d_out;

    unsigned short* Wb = (unsigned short*)d_ws;            // 512*7168 bf16
    const size_t wbytes = (size_t)N_OUT * K_TOT * 2;       // 7.34 MB

    // pick largest chunk (then largest ksplit) that fits ws:
    //   ws = Wb + A[chunk][7168] bf16 + partials (ksplit-1)*chunk*512 bf16
    int chunk = BATCH, ksplit = KSMAX;
    while (chunk > 128 &&
           wbytes + (size_t)chunk * K_TOT * 2 +
           (size_t)(KSMAX - 1) * chunk * N_OUT * 2 > ws_size) chunk >>= 1;
    while (ksplit > 1 &&
           wbytes + (size_t)chunk * K_TOT * 2 +
           (size_t)(ksplit - 1) * chunk * N_OUT * 2 > ws_size) ksplit--;

    unsigned short* Abuf = Wb + (size_t)N_OUT * K_TOT;
    unsigned short* part = Abuf + (size_t)chunk * K_TOT;
    const int kiters = (K_TOT / BK) / ksplit;              // 112/ks, exact

    kan_wconv<<<dim3(K_TOT / 256, N_OUT), 256, 0, stream>>>(base_w, spline_w, Wb);

    for (int row0 = 0; row0 < BATCH; row0 += chunk) {
        kan_prep<<<dim3(chunk), 256, 0, stream>>>(x, Abuf, row0);
        kan_gemm<<<dim3(chunk / BM, N_OUT / BN, ksplit), 256, 0, stream>>>(
            Abuf, Wb, base_b, out, part, row0, kiters, chunk);
        if (ksplit > 1) {
            long n4 = (long)chunk * N_OUT / 4;
            kan_reduce<<<dim3((n4 + 255) / 256), 256, 0, stream>>>(
                out + (long)row0 * N_OUT, part, ksplit - 1, n4);
        }
    }
}

// Round 7
// 183.021 us; speedup vs baseline: 2.5984x; 1.0408x over previous
//
#include <hip/hip_runtime.h>
#include <hip/hip_bf16.h>

// KAN layer as one bf16 GEMM: out[8192,512] = A[8192,7168] @ W[512,7168]^T + b
// A layout is BASIS-MAJOR: col k = plane*512 + i, plane 0 = silu(x_i),
// planes 1..13 = b-spline bases g=0..12 of x_i. W permuted to match.
// R3: m97-style GEMM (global_load_lds w16, 128x128 tile) + split-K partials.
// R4: prep rewritten — register-only, __expf, coalesced ushort2 plane stores.
// R5: LDS XOR bank swizzle -> conflicts 2.2e7 -> 0 (for 16x16 reads).
// R6: 32x32x16 MFMA (VALUBusy 35->11%) + bf16 partials; but 32-row fragment
//     reads re-introduced 4-way conflicts (7.34e6): key R&7 misses row bits 3-4.
// R7: row-aware swizzle key key(R) = (R&7) ^ ((R>>3)&7).
//     Stage: lane l, instr q fetches global chunk (l&7)^sr^4(w&1)^q.
//     Read: physical chunk (2s+hi)^x7^4t^(l32>>3) -> 8 lanes/bank-group, even.

#define BATCH   8192
#define IN_F    512
#define N_OUT   512
#define NG      13            // GRID_SIZE + K
#define NPL     14            // planes: silu + 13 bases
#define K_TOT   7168          // 14 * 512
#define BM      128
#define BN      128
#define BK      64
#define KSMAX   4

typedef short short8 __attribute__((ext_vector_type(8)));
typedef float floatx16 __attribute__((ext_vector_type(16)));

__device__ __forceinline__ unsigned short f2bf(float f) {
    union { float f; unsigned u; } v; v.f = f;
    unsigned r = v.u + 0x7FFFu + ((v.u >> 16) & 1u);   // RNE
    return (unsigned short)(r >> 16);
}
__device__ __forceinline__ float bf2f(unsigned short h) {
    union { unsigned u; float f; } v; v.u = (unsigned)h << 16;
    return v.f;
}

__device__ __forceinline__ void gl2lds16(const unsigned short* g, unsigned short* l) {
    __builtin_amdgcn_global_load_lds(
        (const __attribute__((address_space(1))) unsigned int*)g,
        (__attribute__((address_space(3))) unsigned int*)l, 16, 0, 0);
}

// ---------------- W conversion: Wb[o][plane*512 + i] ----------------
__global__ void kan_wconv(const float* __restrict__ base_w,
                          const float* __restrict__ spline_w,
                          unsigned short* __restrict__ Wb) {
    int c = blockIdx.x * 256 + threadIdx.x;   // 0..7167  (grid.x = 28)
    int o = blockIdx.y;                        // 0..511
    int pl = c >> 9;                           // plane
    int i  = c & 511;
    float v = (pl == 0) ? base_w[o * IN_F + i]
                        : spline_w[(long)o * (IN_F * NG) + i * NG + (pl - 1)];
    Wb[(long)o * K_TOT + c] = f2bf(v);
}

// ---------------- A construction: silu + cubic B-spline bases ----------------
__global__ __launch_bounds__(256)
void kan_prep(const float* __restrict__ X,
              unsigned short* __restrict__ A,
              int row0) {
    const int b  = blockIdx.x;
    const int ip = threadIdx.x;                // feature pair 0..255
    float2 x2 = ((const float2*)(X + (long)(row0 + b) * IN_F))[ip];

    float outv[2][NPL];
#pragma unroll
    for (int e = 0; e < 2; e++) {
        float x = (e == 0) ? x2.x : x2.y;
        outv[e][0] = x * __builtin_amdgcn_rcpf(1.0f + __expf(-x));  // silu

        // cubic Cox-de Boor on uniform knots t_j = -3.2 + 0.4j
        float bb[16];
#pragma unroll
        for (int j = 0; j < 16; j++) {
            float t0 = -3.2f + 0.4f * j;
            bb[j] = (x >= t0 && x < t0 + 0.4f) ? 1.0f : 0.0f;
        }
        const float inv1 = 1.0f / (0.4f + 1e-8f);
        const float inv2 = 1.0f / (0.8f + 1e-8f);
        const float inv3 = 1.0f / (1.2f + 1e-8f);
#pragma unroll
        for (int j = 0; j < 15; j++) {
            float tj = -3.2f + 0.4f * j;
            bb[j] = (x - tj) * inv1 * bb[j] + ((tj + 0.8f) - x) * inv1 * bb[j + 1];
        }
#pragma unroll
        for (int j = 0; j < 14; j++) {
            float tj = -3.2f + 0.4f * j;
            bb[j] = (x - tj) * inv2 * bb[j] + ((tj + 1.2f) - x) * inv2 * bb[j + 1];
        }
#pragma unroll
        for (int j = 0; j < 13; j++) {
            float tj = -3.2f + 0.4f * j;
            bb[j] = (x - tj) * inv3 * bb[j] + ((tj + 1.6f) - x) * inv3 * bb[j + 1];
        }
#pragma unroll
        for (int g = 0; g < NG; g++) outv[e][1 + g] = bb[g];
    }

    unsigned short* arow = A + (long)b * K_TOT + ip * 2;
#pragma unroll
    for (int pl = 0; pl < NPL; pl++) {
        unsigned int pk = (unsigned int)f2bf(outv[0][pl]) |
                          ((unsigned int)f2bf(outv[1][pl]) << 16);
        *(unsigned int*)(arow + pl * IN_F) = pk;
    }
}

// ---------------- GEMM: m97 structure + row-aware swizzle, 32x32x16 MFMA ----------------
__global__ __launch_bounds__(256)
void kan_gemm(const unsigned short* __restrict__ A,   // [chunk][7168] bf16 bits
              const unsigned short* __restrict__ Wb,  // [512][7168]  bf16 bits
              const float* __restrict__ bias,         // [512]
              float* __restrict__ out,                // [8192][512] fp32
              unsigned short* __restrict__ part,      // [(ks-1)][chunk][512] bf16
              int row0, int kiters, int chunk) {
    __shared__ unsigned short As[BM * BK];   // 16 KB; swizzled layout:
    __shared__ unsigned short Bs[BN * BK];   // chunk J of row R at pos J^(R&7)^((R>>3)&7)

    const int lane = threadIdx.x & 63;
    const int wave = threadIdx.x >> 6;
    const int wm   = wave >> 1;      // 0..1
    const int wn   = wave & 1;       // 0..1
    const int l32  = lane & 31;      // mfma 32x32 row/col index
    const int hi   = lane >> 5;      // mfma k-half
    const int x7   = lane & 7;       // low swizzle key bits
    const int b32  = l32 >> 3;       // row bits 3-4 within a 32-row fragment

    const int m0 = blockIdx.x * BM;          // row within chunk
    const int n0 = blockIdx.y * BN;
    const int ks = blockIdx.z;
    const long kbase = (long)ks * kiters * BK;

    // staging: instr q of wave w covers rows w*32+q*8+sr; lane l fetches
    // global chunk (l&7) ^ key(R), key(R) = (R&7)^((R>>3)&7) = sr^(4*(w&1)+q)
    const int sr = lane >> 3;                // 0..7

    const unsigned short* gA[4];
    const unsigned short* gB[4];
#pragma unroll
    for (int q = 0; q < 4; q++) {
        int scs = ((lane & 7) ^ sr ^ ((4 * (wave & 1) + q) & 7)) * 8;
        gA[q] = A  + (long)(m0 + wave * 32 + q * 8 + sr) * K_TOT + kbase + scs;
        gB[q] = Wb + (long)(n0 + wave * 32 + q * 8 + sr) * K_TOT + kbase + scs;
    }
    unsigned short* lA = As + (wave * 32) * BK;   // wave-uniform base
    unsigned short* lB = Bs + (wave * 32) * BK;

    floatx16 acc[2][2];
#pragma unroll
    for (int i = 0; i < 2; i++)
#pragma unroll
        for (int j = 0; j < 2; j++)
#pragma unroll
            for (int r = 0; r < 16; r++) acc[i][j][r] = 0.0f;

    for (int kk = 0; kk < kiters; kk++) {
        __syncthreads();                     // prior compute done before overwrite
#pragma unroll
        for (int q = 0; q < 4; q++) {
            gl2lds16(gA[q], lA + q * 8 * BK);
            gl2lds16(gB[q], lB + q * 8 * BK);
            gA[q] += BK; gB[q] += BK;
        }
        __syncthreads();                     // drains vmcnt (compiler-inserted)

#pragma unroll
        for (int s = 0; s < 4; s++) {        // four k=16 MFMA steps per BK=64
            short8 af[2], bf[2];
#pragma unroll
            for (int t = 0; t < 2; t++) {    // physical chunk = J ^ key(row)
                const int cofs = (((2 * s + hi) ^ x7 ^ (4 * t) ^ b32) & 7) * 8;
                af[t] = *(const short8*)(As + (wm * 64 + t * 32 + l32) * BK + cofs);
                bf[t] = *(const short8*)(Bs + (wn * 64 + t * 32 + l32) * BK + cofs);
            }
#pragma unroll
            for (int i = 0; i < 2; i++)
#pragma unroll
                for (int j = 0; j < 2; j++)
                    acc[i][j] = __builtin_amdgcn_mfma_f32_32x32x16_bf16(
                        af[i], bf[j], acc[i][j], 0, 0, 0);
        }
    }

    // epilogue: 32x32 C/D layout col=lane&31, row=(reg&3)+8*(reg>>2)+4*hi
    if (ks == 0) {
        float* dst = out + (long)row0 * N_OUT;
#pragma unroll
        for (int i = 0; i < 2; i++) {
            int r0 = m0 + wm * 64 + i * 32 + 4 * hi;
#pragma unroll
            for (int j = 0; j < 2; j++) {
                int col = n0 + wn * 64 + j * 32 + l32;
                float bv = bias[col];
#pragma unroll
                for (int reg = 0; reg < 16; reg++) {
                    int row = r0 + (reg & 3) + 8 * (reg >> 2);
                    dst[(long)row * N_OUT + col] = acc[i][j][reg] + bv;
                }
            }
        }
    } else {
        unsigned short* dst = part + (long)(ks - 1) * chunk * N_OUT;
#pragma unroll
        for (int i = 0; i < 2; i++) {
            int r0 = m0 + wm * 64 + i * 32 + 4 * hi;
#pragma unroll
            for (int j = 0; j < 2; j++) {
                int col = n0 + wn * 64 + j * 32 + l32;
#pragma unroll
                for (int reg = 0; reg < 16; reg++) {
                    int row = r0 + (reg & 3) + 8 * (reg >> 2);
                    dst[(long)row * N_OUT + col] = f2bf(acc[i][j][reg]);
                }
            }
        }
    }
}

// ---------------- partial reduction: out += sum(bf16 partials) ----------------
__global__ void kan_reduce(float* __restrict__ out,               // chunk*512 fp32
                           const unsigned short* __restrict__ part,
                           int ns, long n4) {                     // n4 = chunk*512/4
    long t = (long)blockIdx.x * 256 + threadIdx.x;
    if (t >= n4) return;
    float4 v = ((const float4*)out)[t];
    for (int s = 0; s < ns; s++) {
        ushort4 p = ((const ushort4*)part)[s * n4 + t];
        v.x += bf2f(p.x); v.y += bf2f(p.y); v.z += bf2f(p.z); v.w += bf2f(p.w);
    }
    ((float4*)out)[t] = v;
}

extern "C" void kernel_launch(void* const* d_in, const int* in_sizes, int n_in,
                              void* d_out, int out_size, void* d_ws, size_t ws_size,
                              hipStream_t stream) {
    const float* x        = (const float*)d_in[0];
    const float* base_w   = (const float*)d_in[1];
    const float* base_b   = (const float*)d_in[2];
    const float* spline_w = (const float*)d_in[3];
    float* out = (float*)d_out;

    unsigned short* Wb = (unsigned short*)d_ws;            // 512*7168 bf16
    const size_t wbytes = (size_t)N_OUT * K_TOT * 2;       // 7.34 MB

    // pick largest chunk (then largest ksplit) that fits ws:
    //   ws = Wb + A[chunk][7168] bf16 + partials (ksplit-1)*chunk*512 bf16
    int chunk = BATCH, ksplit = KSMAX;
    while (chunk > 128 &&
           wbytes + (size_t)chunk * K_TOT * 2 +
           (size_t)(KSMAX - 1) * chunk * N_OUT * 2 > ws_size) chunk >>= 1;
    while (ksplit > 1 &&
           wbytes + (size_t)chunk * K_TOT * 2 +
           (size_t)(ksplit - 1) * chunk * N_OUT * 2 > ws_size) ksplit--;

    unsigned short* Abuf = Wb + (size_t)N_OUT * K_TOT;
    unsigned short* part = Abuf + (size_t)chunk * K_TOT;
    const int kiters = (K_TOT / BK) / ksplit;              // 112/ks, exact

    kan_wconv<<<dim3(K_TOT / 256, N_OUT), 256, 0, stream>>>(base_w, spline_w, Wb);

    for (int row0 = 0; row0 < BATCH; row0 += chunk) {
        kan_prep<<<dim3(chunk), 256, 0, stream>>>(x, Abuf, row0);
        kan_gemm<<<dim3(chunk / BM, N_OUT / BN, ksplit), 256, 0, stream>>>(
            Abuf, Wb, base_b, out, part, row0, kiters, chunk);
        if (ksplit > 1) {
            long n4 = (long)chunk * N_OUT / 4;
            kan_reduce<<<dim3((n4 + 255) / 256), 256, 0, stream>>>(
                out + (long)row0 * N_OUT, part, ksplit - 1, n4);
        }
    }
}

// Round 8
// 177.991 us; speedup vs baseline: 2.6719x; 1.0283x over previous
//
#include <hip/hip_runtime.h>
#include <hip/hip_bf16.h>

// KAN layer as one bf16 GEMM: out[8192,512] = A[8192,7168] @ W[512,7168]^T + b
// A layout is BASIS-MAJOR: col k = plane*512 + i, plane 0 = silu(x_i),
// planes 1..13 = b-spline bases g=0..12 of x_i. W permuted to match.
// R3: m97-style GEMM (global_load_lds w16, 128x128 tile) + split-K partials.
// R4: prep rewritten — register-only, __expf, coalesced ushort2 plane stores.
// R5: LDS XOR bank swizzle -> conflicts 2.2e7 -> 0 (for 16x16 reads).
// R6: 32x32x16 MFMA (VALUBusy 35->11%) + bf16 partials.
// R7: row-aware swizzle key (R&7)^((R>>3)&7) -> conflicts 0, gemm 75.5us.
// R8: consolidation — ksplit 4->2 (plane-aligned; halves partial+reduce
//     traffic, 512 blocks = 2/CU matches observed residency) and wconv
//     merged into the prep launch (one fewer dispatch gap). Hot loop untouched.

#define BATCH   8192
#define IN_F    512
#define N_OUT   512
#define NG      13            // GRID_SIZE + K
#define NPL     14            // planes: silu + 13 bases
#define K_TOT   7168          // 14 * 512
#define BM      128
#define BN      128
#define BK      64
#define KSMAX   2

typedef short short8 __attribute__((ext_vector_type(8)));
typedef float floatx16 __attribute__((ext_vector_type(16)));

__device__ __forceinline__ unsigned short f2bf(float f) {
    union { float f; unsigned u; } v; v.f = f;
    unsigned r = v.u + 0x7FFFu + ((v.u >> 16) & 1u);   // RNE
    return (unsigned short)(r >> 16);
}
__device__ __forceinline__ float bf2f(unsigned short h) {
    union { unsigned u; float f; } v; v.u = (unsigned)h << 16;
    return v.f;
}

__device__ __forceinline__ void gl2lds16(const unsigned short* g, unsigned short* l) {
    __builtin_amdgcn_global_load_lds(
        (const __attribute__((address_space(1))) unsigned int*)g,
        (__attribute__((address_space(3))) unsigned int*)l, 16, 0, 0);
}

// ---------------- aux: prep (blocks [0,nprep)) + wconv (blocks [nprep,nprep+nw)) ----
// prep: one block per batch row; silu + cubic B-spline bases, register-only,
//       coalesced ushort2 stores into basis-major planes.
// wconv: one block per output row o; Wb[o][pl*512+i] from base_w / spline_w.
__global__ __launch_bounds__(256)
void kan_aux(const float* __restrict__ X,
             unsigned short* __restrict__ A,
             const float* __restrict__ base_w,
             const float* __restrict__ spline_w,
             unsigned short* __restrict__ Wb,
             int row0, int nprep) {
    if ((int)blockIdx.x >= nprep) {
        // ---- wconv part ----
        int o = blockIdx.x - nprep;            // 0..511
        for (int c = threadIdx.x; c < K_TOT; c += 256) {
            int pl = c >> 9;
            int i  = c & 511;
            float v = (pl == 0) ? base_w[o * IN_F + i]
                                : spline_w[(long)o * (IN_F * NG) + i * NG + (pl - 1)];
            Wb[(long)o * K_TOT + c] = f2bf(v);
        }
        return;
    }
    // ---- prep part ----
    const int b  = blockIdx.x;
    const int ip = threadIdx.x;                // feature pair 0..255
    float2 x2 = ((const float2*)(X + (long)(row0 + b) * IN_F))[ip];

    float outv[2][NPL];
#pragma unroll
    for (int e = 0; e < 2; e++) {
        float x = (e == 0) ? x2.x : x2.y;
        outv[e][0] = x * __builtin_amdgcn_rcpf(1.0f + __expf(-x));  // silu

        // cubic Cox-de Boor on uniform knots t_j = -3.2 + 0.4j
        float bb[16];
#pragma unroll
        for (int j = 0; j < 16; j++) {
            float t0 = -3.2f + 0.4f * j;
            bb[j] = (x >= t0 && x < t0 + 0.4f) ? 1.0f : 0.0f;
        }
        const float inv1 = 1.0f / (0.4f + 1e-8f);
        const float inv2 = 1.0f / (0.8f + 1e-8f);
        const float inv3 = 1.0f / (1.2f + 1e-8f);
#pragma unroll
        for (int j = 0; j < 15; j++) {
            float tj = -3.2f + 0.4f * j;
            bb[j] = (x - tj) * inv1 * bb[j] + ((tj + 0.8f) - x) * inv1 * bb[j + 1];
        }
#pragma unroll
        for (int j = 0; j < 14; j++) {
            float tj = -3.2f + 0.4f * j;
            bb[j] = (x - tj) * inv2 * bb[j] + ((tj + 1.2f) - x) * inv2 * bb[j + 1];
        }
#pragma unroll
        for (int j = 0; j < 13; j++) {
            float tj = -3.2f + 0.4f * j;
            bb[j] = (x - tj) * inv3 * bb[j] + ((tj + 1.6f) - x) * inv3 * bb[j + 1];
        }
#pragma unroll
        for (int g = 0; g < NG; g++) outv[e][1 + g] = bb[g];
    }

    unsigned short* arow = A + (long)b * K_TOT + ip * 2;
#pragma unroll
    for (int pl = 0; pl < NPL; pl++) {
        unsigned int pk = (unsigned int)f2bf(outv[0][pl]) |
                          ((unsigned int)f2bf(outv[1][pl]) << 16);
        *(unsigned int*)(arow + pl * IN_F) = pk;
    }
}

// ---------------- GEMM: m97 structure + row-aware swizzle, 32x32x16 MFMA ----------------
__global__ __launch_bounds__(256)
void kan_gemm(const unsigned short* __restrict__ A,   // [chunk][7168] bf16 bits
              const unsigned short* __restrict__ Wb,  // [512][7168]  bf16 bits
              const float* __restrict__ bias,         // [512]
              float* __restrict__ out,                // [8192][512] fp32
              unsigned short* __restrict__ part,      // [(ks-1)][chunk][512] bf16
              int row0, int kiters, int chunk) {
    __shared__ unsigned short As[BM * BK];   // 16 KB; swizzled layout:
    __shared__ unsigned short Bs[BN * BK];   // chunk J of row R at pos J^(R&7)^((R>>3)&7)

    const int lane = threadIdx.x & 63;
    const int wave = threadIdx.x >> 6;
    const int wm   = wave >> 1;      // 0..1
    const int wn   = wave & 1;       // 0..1
    const int l32  = lane & 31;      // mfma 32x32 row/col index
    const int hi   = lane >> 5;      // mfma k-half
    const int x7   = lane & 7;       // low swizzle key bits
    const int b32  = l32 >> 3;       // row bits 3-4 within a 32-row fragment

    const int m0 = blockIdx.x * BM;          // row within chunk
    const int n0 = blockIdx.y * BN;
    const int ks = blockIdx.z;
    const long kbase = (long)ks * kiters * BK;

    // staging: instr q of wave w covers rows w*32+q*8+sr; lane l fetches
    // global chunk (l&7) ^ key(R), key(R) = (R&7)^((R>>3)&7) = sr^(4*(w&1)+q)
    const int sr = lane >> 3;                // 0..7

    const unsigned short* gA[4];
    const unsigned short* gB[4];
#pragma unroll
    for (int q = 0; q < 4; q++) {
        int scs = ((lane & 7) ^ sr ^ ((4 * (wave & 1) + q) & 7)) * 8;
        gA[q] = A  + (long)(m0 + wave * 32 + q * 8 + sr) * K_TOT + kbase + scs;
        gB[q] = Wb + (long)(n0 + wave * 32 + q * 8 + sr) * K_TOT + kbase + scs;
    }
    unsigned short* lA = As + (wave * 32) * BK;   // wave-uniform base
    unsigned short* lB = Bs + (wave * 32) * BK;

    floatx16 acc[2][2];
#pragma unroll
    for (int i = 0; i < 2; i++)
#pragma unroll
        for (int j = 0; j < 2; j++)
#pragma unroll
            for (int r = 0; r < 16; r++) acc[i][j][r] = 0.0f;

    for (int kk = 0; kk < kiters; kk++) {
        __syncthreads();                     // prior compute done before overwrite
#pragma unroll
        for (int q = 0; q < 4; q++) {
            gl2lds16(gA[q], lA + q * 8 * BK);
            gl2lds16(gB[q], lB + q * 8 * BK);
            gA[q] += BK; gB[q] += BK;
        }
        __syncthreads();                     // drains vmcnt (compiler-inserted)

#pragma unroll
        for (int s = 0; s < 4; s++) {        // four k=16 MFMA steps per BK=64
            short8 af[2], bf[2];
#pragma unroll
            for (int t = 0; t < 2; t++) {    // physical chunk = J ^ key(row)
                const int cofs = (((2 * s + hi) ^ x7 ^ (4 * t) ^ b32) & 7) * 8;
                af[t] = *(const short8*)(As + (wm * 64 + t * 32 + l32) * BK + cofs);
                bf[t] = *(const short8*)(Bs + (wn * 64 + t * 32 + l32) * BK + cofs);
            }
#pragma unroll
            for (int i = 0; i < 2; i++)
#pragma unroll
                for (int j = 0; j < 2; j++)
                    acc[i][j] = __builtin_amdgcn_mfma_f32_32x32x16_bf16(
                        af[i], bf[j], acc[i][j], 0, 0, 0);
        }
    }

    // epilogue: 32x32 C/D layout col=lane&31, row=(reg&3)+8*(reg>>2)+4*hi
    if (ks == 0) {
        float* dst = out + (long)row0 * N_OUT;
#pragma unroll
        for (int i = 0; i < 2; i++) {
            int r0 = m0 + wm * 64 + i * 32 + 4 * hi;
#pragma unroll
            for (int j = 0; j < 2; j++) {
                int col = n0 + wn * 64 + j * 32 + l32;
                float bv = bias[col];
#pragma unroll
                for (int reg = 0; reg < 16; reg++) {
                    int row = r0 + (reg & 3) + 8 * (reg >> 2);
                    dst[(long)row * N_OUT + col] = acc[i][j][reg] + bv;
                }
            }
        }
    } else {
        unsigned short* dst = part + (long)(ks - 1) * chunk * N_OUT;
#pragma unroll
        for (int i = 0; i < 2; i++) {
            int r0 = m0 + wm * 64 + i * 32 + 4 * hi;
#pragma unroll
            for (int j = 0; j < 2; j++) {
                int col = n0 + wn * 64 + j * 32 + l32;
#pragma unroll
                for (int reg = 0; reg < 16; reg++) {
                    int row = r0 + (reg & 3) + 8 * (reg >> 2);
                    dst[(long)row * N_OUT + col] = f2bf(acc[i][j][reg]);
                }
            }
        }
    }
}

// ---------------- partial reduction: out += sum(bf16 partials) ----------------
__global__ void kan_reduce(float* __restrict__ out,               // chunk*512 fp32
                           const unsigned short* __restrict__ part,
                           int ns, long n4) {                     // n4 = chunk*512/4
    long t = (long)blockIdx.x * 256 + threadIdx.x;
    if (t >= n4) return;
    float4 v = ((const float4*)out)[t];
    for (int s = 0; s < ns; s++) {
        ushort4 p = ((const ushort4*)part)[s * n4 + t];
        v.x += bf2f(p.x); v.y += bf2f(p.y); v.z += bf2f(p.z); v.w += bf2f(p.w);
    }
    ((float4*)out)[t] = v;
}

extern "C" void kernel_launch(void* const* d_in, const int* in_sizes, int n_in,
                              void* d_out, int out_size, void* d_ws, size_t ws_size,
                              hipStream_t stream) {
    const float* x        = (const float*)d_in[0];
    const float* base_w   = (const float*)d_in[1];
    const float* base_b   = (const float*)d_in[2];
    const float* spline_w = (const float*)d_in[3];
    float* out = (float*)d_out;

    unsigned short* Wb = (unsigned short*)d_ws;            // 512*7168 bf16
    const size_t wbytes = (size_t)N_OUT * K_TOT * 2;       // 7.34 MB

    // pick largest chunk (then largest ksplit) that fits ws:
    //   ws = Wb + A[chunk][7168] bf16 + partials (ksplit-1)*chunk*512 bf16
    int chunk = BATCH, ksplit = KSMAX;
    while (chunk > 128 &&
           wbytes + (size_t)chunk * K_TOT * 2 +
           (size_t)(KSMAX - 1) * chunk * N_OUT * 2 > ws_size) chunk >>= 1;
    while (ksplit > 1 &&
           wbytes + (size_t)chunk * K_TOT * 2 +
           (size_t)(ksplit - 1) * chunk * N_OUT * 2 > ws_size) ksplit--;

    unsigned short* Abuf = Wb + (size_t)N_OUT * K_TOT;
    unsigned short* part = Abuf + (size_t)chunk * K_TOT;
    const int kiters = (K_TOT / BK) / ksplit;              // 112/ks, exact

    bool first = true;
    for (int row0 = 0; row0 < BATCH; row0 += chunk) {
        // merged prep(+wconv on the first launch)
        int nw = first ? N_OUT : 0;
        kan_aux<<<dim3(chunk + nw), 256, 0, stream>>>(
            x, Abuf, base_w, spline_w, Wb, row0, chunk);
        first = false;
        kan_gemm<<<dim3(chunk / BM, N_OUT / BN, ksplit), 256, 0, stream>>>(
            Abuf, Wb, base_b, out, part, row0, kiters, chunk);
        if (ksplit > 1) {
            long n4 = (long)chunk * N_OUT / 4;
            kan_reduce<<<dim3((n4 + 255) / 256), 256, 0, stream>>>(
                out + (long)row0 * N_OUT, part, ksplit - 1, n4);
        }
    }
}